// Round 7
// baseline (509.139 us; speedup 1.0000x reference)
//
#include <hip/hip_runtime.h>
#include <math.h>

// B=8,T=2048,D=512,N=4096
static constexpr int D    = 512;
static constexpr int NPOS = 4096;
static constexpr int M    = 16384;
static constexpr float MIN_SCALE = 0.05f;

typedef unsigned short u16;
typedef __attribute__((ext_vector_type(8)))  short short8_t;   // bf16x8 MFMA frag
typedef __attribute__((ext_vector_type(16))) float f32x16_t;   // 32x32 MFMA acc
typedef __attribute__((ext_vector_type(8)))  unsigned short ushort8_t;
typedef __attribute__((ext_vector_type(4)))  unsigned short ushort4_t;

__device__ __forceinline__ u16 f2bf(float f) {
    unsigned u = __float_as_uint(f);
    unsigned r = (u + 0x7FFFu + ((u >> 16) & 1u)) >> 16;  // RN-even
    return (u16)r;
}
__device__ __forceinline__ void async16(void* lds, const void* gp) {
    __builtin_amdgcn_global_load_lds(
        (const __attribute__((address_space(1))) unsigned int*)gp,
        (__attribute__((address_space(3))) unsigned int*)lds, 16, 0, 0);
}

// ws layout: f32 pn[4096] | f32 nl2[4096] (-log2e/et) | f32 xn[16384]
// byte 98304:   PB3 u16 frag-packed  (ng,kg): n=ng*32+(l&31), k=kg*16+(l>>5)*8+c   (4 MB)
// byte 4292608: VT3 u16 frag-packed  (dg,kga): d=dg*32+(l&31), n=kga*16+(l>>5)*8+c (4 MB)
// byte 8486912: XB3 u16 frag-packed  (mg,kg): m=mg*32+(l&31), k=kg*16+(l>>5)*8+c   (16 MB)

__global__ __launch_bounds__(256) void pre_kernel(
    const float* __restrict__ x, const float* __restrict__ pos,
    const float* __restrict__ val, const float* __restrict__ temperature,
    const float* __restrict__ frozen_scale, const int* __restrict__ frozen,
    float* __restrict__ ws_f, u16* __restrict__ pb3, u16* __restrict__ vt3,
    u16* __restrict__ xb3)
{
    const int b   = blockIdx.x;
    const int tid = threadIdx.x;
    const int wv  = tid >> 6, lane = tid & 63;

    if (b < 128) {  // pn / nl2 : 512 waves x 8 rows
        #pragma unroll
        for (int i = 0; i < 8; ++i) {
            const int n = (b * 4 + wv) * 8 + i;
            const float* row = pos + (size_t)n * D;
            float s = 0.f;
            #pragma unroll
            for (int q = 0; q < D; q += 64) { float v = row[q + lane]; s += v * v; }
            #pragma unroll
            for (int off = 32; off > 0; off >>= 1) s += __shfl_down(s, off, 64);
            if (lane == 0) {
                ws_f[n] = s;
                float es = (frozen[n] != 0) ? frozen_scale[n] : MIN_SCALE;
                float et = (fabsf(temperature[n]) + 0.1f) * es;
                ws_f[NPOS + n] = -1.4426950408889634f / et;   // -log2(e)/et
            }
        }
    } else if (b < 640) {  // xn : 2048 waves x 8 rows
        #pragma unroll
        for (int i = 0; i < 8; ++i) {
            const int m = ((b - 128) * 4 + wv) * 8 + i;
            const float* row = x + (size_t)m * D;
            float s = 0.f;
            #pragma unroll
            for (int q = 0; q < D; q += 64) { float v = row[q + lane]; s += v * v; }
            #pragma unroll
            for (int off = 32; off > 0; off >>= 1) s += __shfl_down(s, off, 64);
            if (lane == 0) ws_f[2 * NPOS + m] = s;
        }
    } else if (b < 1664) {  // XB3 pack: 1.048M lane-tasks, 1024 blocks x 4 reps
        const int t = (b - 640) * 256 + tid;
        #pragma unroll
        for (int rep = 0; rep < 4; ++rep) {
            const size_t f = (size_t)t + (size_t)rep * 262144;
            const int l  = (int)(f & 63);
            const int kg = (int)((f >> 6) & 31);
            const int mg = (int)(f >> 11);
            const float* src = x + ((size_t)(mg * 32 + (l & 31)) * D
                                    + kg * 16 + (l >> 5) * 8);
            const float4 a = *(const float4*)src;
            const float4 c = *(const float4*)(src + 4);
            ushort8_t v;
            v[0]=f2bf(a.x); v[1]=f2bf(a.y); v[2]=f2bf(a.z); v[3]=f2bf(a.w);
            v[4]=f2bf(c.x); v[5]=f2bf(c.y); v[6]=f2bf(c.z); v[7]=f2bf(c.w);
            *(ushort8_t*)(xb3 + f * 8) = v;
        }
    } else if (b < 1920) {  // PB3 pack: 262144 lane-tasks, 256 blocks x 4 reps
        const int t = (b - 1664) * 256 + tid;
        #pragma unroll
        for (int rep = 0; rep < 4; ++rep) {
            const size_t f = (size_t)t + (size_t)rep * 65536;
            const int l  = (int)(f & 63);
            const int kg = (int)((f >> 6) & 31);
            const int ng = (int)(f >> 11);
            const float* src = pos + ((size_t)(ng * 32 + (l & 31)) * D
                                      + kg * 16 + (l >> 5) * 8);
            const float4 a = *(const float4*)src;
            const float4 c = *(const float4*)(src + 4);
            ushort8_t v;
            v[0]=f2bf(a.x); v[1]=f2bf(a.y); v[2]=f2bf(a.z); v[3]=f2bf(a.w);
            v[4]=f2bf(c.x); v[5]=f2bf(c.y); v[6]=f2bf(c.z); v[7]=f2bf(c.w);
            *(ushort8_t*)(pb3 + f * 8) = v;
        }
    } else {  // VT3 pack: 512 blocks, 64n x 64d LDS transpose
        __shared__ __attribute__((aligned(16))) float tile[64 * 68];
        const int b2 = b - 1920;
        const int n0 = (b2 & 63) * 64, d0 = (b2 >> 6) * 64;
        {
            const int row = tid >> 2, c0 = (tid & 3) * 16;
            const float* src = val + (size_t)(n0 + row) * D + d0 + c0;
            #pragma unroll
            for (int i = 0; i < 4; ++i)
                *(float4*)&tile[row * 68 + c0 + i * 4] = *(const float4*)(src + i * 4);
        }
        __syncthreads();
        #pragma unroll
        for (int ff = 0; ff < 2; ++ff) {
            const int fidx = ff * 256 + tid;
            const int l    = fidx & 63;
            const int kgl  = (fidx >> 6) & 3;
            const int dgl  = (fidx >> 8) & 1;
            const int d_loc  = dgl * 32 + (l & 31);
            const int n_base = kgl * 16 + (l >> 5) * 8;
            ushort8_t v;
            #pragma unroll
            for (int c = 0; c < 8; ++c) v[c] = f2bf(tile[(n_base + c) * 68 + d_loc]);
            const int dg  = (d0 >> 5) + dgl;
            const int kga = (n0 >> 4) + kgl;
            *(ushort8_t*)(vt3 + ((size_t)(dg * 256 + kga) * 64 + l) * 8) = v;
        }
    }
}

// ---------------------------------------------------------------------------
// Main: 256 blocks x 512 threads (8 waves). m-tile 64, n-tile 256.
// Wave wq owns n-slice [wq*32,+32) in GEMM1 and d-slice [wq*64,+64) in GEMM2
// -> every pb/vt frag loaded exactly once per block (no redundancy).
// x frags staged per k-chunk into 32KB LDS (restaged per tile, L2-cheap).
// LDS 66KB -> 2 blocks/CU.
// ---------------------------------------------------------------------------
__global__ __launch_bounds__(512, 4) void tidal_main(
    const float* __restrict__ ws_f, const u16* __restrict__ pb3,
    const u16* __restrict__ vt3, const u16* __restrict__ xb3,
    float* __restrict__ out)
{
    __shared__ __attribute__((aligned(16))) u16 XBL[32][512];  // [kgl*2+mh] 32KB
    __shared__ __attribute__((aligned(16))) u16 WTF[32][512];  // [kg*2+mh]  32KB
    __shared__ float red[8][64];
    __shared__ float inv_s[64];

    const float* pn_a = ws_f;
    const float* nl_a = ws_f + NPOS;
    const float* xn_a = ws_f + 2 * NPOS;

    const int tid = threadIdx.x;
    const int lane = tid & 63;
    const int wq   = tid >> 6;      // 0..7
    const int h    = lane >> 5;
    const int l31  = lane & 31;
    const int m0   = blockIdx.x * 64;

    const float xn0 = xn_a[m0 + l31];
    const float xn1 = xn_a[m0 + 32 + l31];

    f32x16_t O00 = (f32x16_t)0.f, O01 = (f32x16_t)0.f;
    f32x16_t O10 = (f32x16_t)0.f, O11 = (f32x16_t)0.f;
    float den0 = 0.f, den1 = 0.f;

    for (int tile = 0; tile < NPOS / 256; ++tile) {
        // ---------------- GEMM1: S^T = pb @ x^T, m=64 per wave ----------------
        f32x16_t S0 = (f32x16_t)0.f, S1 = (f32x16_t)0.f;
        const u16* pbw = pb3 + (size_t)((tile * 8 + wq) * 32) * 512;

        #pragma unroll
        for (int kh = 0; kh < 2; ++kh) {
            __syncthreads();   // XBL WAR (prev users done / prev GEMM2 done)
            #pragma unroll
            for (int s = 0; s < 4; ++s) {
                const int seg = wq * 4 + s;          // 0..31 = kgl*2+mh
                const int kgl = seg >> 1, mh = seg & 1;
                const u16* gp = xb3
                    + (size_t)((2 * blockIdx.x + mh) * 32 + kh * 16 + kgl) * 512
                    + lane * 8;
                async16(&XBL[seg][0], gp);
            }
            __syncthreads();   // staged ready (vmcnt drained at barrier)
            #pragma unroll 4
            for (int kgl = 0; kgl < 16; ++kgl) {
                const short8_t A  = *(const short8_t*)(pbw + (size_t)(kh * 16 + kgl) * 512 + lane * 8);
                const short8_t B0 = *(const short8_t*)&XBL[kgl * 2 + 0][lane * 8];
                const short8_t B1 = *(const short8_t*)&XBL[kgl * 2 + 1][lane * 8];
                S0 = __builtin_amdgcn_mfma_f32_32x32x16_bf16(A, B0, S0, 0, 0, 0);
                S1 = __builtin_amdgcn_mfma_f32_32x32x16_bf16(A, B1, S1, 0, 0, 0);
            }
        }

        // ------------- epilogue: w = exp2(nl2*sqrt(d2)) -> WTF frags -------------
        #pragma unroll
        for (int g = 0; g < 4; ++g) {
            const int nn = 8 * g + 4 * h;            // n_rel base (r adds 0..3)
            const int nb = tile * 256 + wq * 32 + nn;
            const float4 pn4 = *(const float4*)(pn_a + nb);
            const float4 nl4 = *(const float4*)(nl_a + nb);
            const float pnv[4] = {pn4.x, pn4.y, pn4.z, pn4.w};
            const float nlv[4] = {nl4.x, nl4.y, nl4.z, nl4.w};
            ushort4_t w0, w1;
            #pragma unroll
            for (int r = 0; r < 4; ++r) {
                float d2 = fmaxf(fmaf(-2.f, S0[4 * g + r], xn0 + pnv[r]), 0.f);
                float w  = __builtin_amdgcn_exp2f(__builtin_amdgcn_sqrtf(d2) * nlv[r]);
                den0 += w; w0[r] = f2bf(w);
                d2 = fmaxf(fmaf(-2.f, S1[4 * g + r], xn1 + pnv[r]), 0.f);
                w  = __builtin_amdgcn_exp2f(__builtin_amdgcn_sqrtf(d2) * nlv[r]);
                den1 += w; w1[r] = f2bf(w);
            }
            const int kgn = 2 * wq + (nn >> 4);      // frag n-group within tile
            const int sub = nn & 15;
            const int h2  = sub >> 3, cb = sub & 7;
            *(ushort4_t*)&WTF[kgn * 2 + 0][(l31 + 32 * h2) * 8 + cb] = w0;
            *(ushort4_t*)&WTF[kgn * 2 + 1][(l31 + 32 * h2) * 8 + cb] = w1;
        }
        __syncthreads();   // WTF ready

        // ---------------- GEMM2: O += W @ V, d=64 per wave ----------------
        const u16* vt0 = vt3 + (size_t)((2 * wq)     * 256 + tile * 16) * 512;
        const u16* vt1 = vt3 + (size_t)((2 * wq + 1) * 256 + tile * 16) * 512;
        #pragma unroll 2
        for (int kg = 0; kg < 16; ++kg) {
            const short8_t A0 = *(const short8_t*)&WTF[kg * 2 + 0][lane * 8];
            const short8_t A1 = *(const short8_t*)&WTF[kg * 2 + 1][lane * 8];
            const short8_t B0 = *(const short8_t*)(vt0 + (size_t)kg * 512 + lane * 8);
            const short8_t B1 = *(const short8_t*)(vt1 + (size_t)kg * 512 + lane * 8);
            O00 = __builtin_amdgcn_mfma_f32_32x32x16_bf16(A0, B0, O00, 0, 0, 0);
            O01 = __builtin_amdgcn_mfma_f32_32x32x16_bf16(A0, B1, O01, 0, 0, 0);
            O10 = __builtin_amdgcn_mfma_f32_32x32x16_bf16(A1, B0, O10, 0, 0, 0);
            O11 = __builtin_amdgcn_mfma_f32_32x32x16_bf16(A1, B1, O11, 0, 0, 0);
        }
    }

    // ---------------- den reduce + normalize + store ----------------
    den0 += __shfl_xor(den0, 32, 64);
    den1 += __shfl_xor(den1, 32, 64);
    if (lane < 32) { red[wq][l31] = den0; red[wq][32 + l31] = den1; }
    __syncthreads();
    if (tid < 64) {
        float s2 = 0.f;
        #pragma unroll
        for (int j = 0; j < 8; ++j) s2 += red[j][tid];
        inv_s[tid] = 1.f / (s2 + 1e-8f);
    }
    __syncthreads();

    const int d0c = 2 * wq * 32 + l31;
    const int d1c = (2 * wq + 1) * 32 + l31;
    #pragma unroll
    for (int g = 0; g < 4; ++g) {
        #pragma unroll
        for (int r = 0; r < 4; ++r) {
            const int mr = r + 8 * g + 4 * h;        // row within 32
            const float i0 = inv_s[mr];
            const float i1 = inv_s[32 + mr];
            float* o0 = out + (size_t)(m0 + mr) * D;
            float* o1 = out + (size_t)(m0 + 32 + mr) * D;
            o0[d0c] = O00[4 * g + r] * i0;
            o0[d1c] = O01[4 * g + r] * i0;
            o1[d0c] = O10[4 * g + r] * i1;
            o1[d1c] = O11[4 * g + r] * i1;
        }
    }
}

extern "C" void kernel_launch(void* const* d_in, const int* in_sizes, int n_in,
                              void* d_out, int out_size, void* d_ws, size_t ws_size,
                              hipStream_t stream) {
    const float* xp  = (const float*)d_in[0];
    const float* pos = (const float*)d_in[1];
    const float* val = (const float*)d_in[2];
    const float* tmp = (const float*)d_in[3];
    const float* fsc = (const float*)d_in[4];
    const int*   frz = (const int*)d_in[5];
    float* outp = (float*)d_out;

    float* ws_f = (float*)d_ws;
    u16*   pb3  = (u16*)((char*)d_ws + 98304);
    u16*   vt3  = (u16*)((char*)d_ws + 4292608);
    u16*   xb3  = (u16*)((char*)d_ws + 8486912);

    pre_kernel<<<2432, 256, 0, stream>>>(xp, pos, val, tmp, fsc, frz,
                                         ws_f, pb3, vt3, xb3);
    tidal_main<<<M / 64, 512, 0, stream>>>(ws_f, pb3, vt3, xb3, outp);
}